// Round 23
// baseline (257.319 us; speedup 1.0000x reference)
//
#include <hip/hip_runtime.h>
#include <hip/hip_fp16.h>

// GNNPolicy forward: 2-layer GCN + actor head + mean-pool critic head.
// N=100K, E=1.6M, H=64, G=64. CSR build: 2-level counting sort; per-node
// segments padded to mult of 8 (uniform 8-edge gather body, unroll 2). xw/h
// fp16 (f32 accum). passA fused with gemm1 (global_load_lds dbuf staging).
// Pool/value separate (R16 lesson). R23: pool_k uses BOTH wave halves as
// independent 32-lane chunk processors (was: lanes>=32 idle) + 8192 chunks.

#define TB 256
#define BSH2 9
#define BW2 512          // nodes per coarse bucket
#define CHUNK 4096       // edges per passA block
#define NB1MAX 256       // max coarse buckets (N <= 131072, row fits 17 bits)
#define PAD 8            // per-node segment padding multiple

#define FMA_ROW(ar, xv)                                                        \
    ar.x = fmaf(xv.x, w0.x, ar.x); ar.y = fmaf(xv.x, w0.y, ar.y);              \
    ar.z = fmaf(xv.x, w0.z, ar.z); ar.w = fmaf(xv.x, w0.w, ar.w);              \
    ar.x = fmaf(xv.y, w1.x, ar.x); ar.y = fmaf(xv.y, w1.y, ar.y);              \
    ar.z = fmaf(xv.y, w1.z, ar.z); ar.w = fmaf(xv.y, w1.w, ar.w);              \
    ar.x = fmaf(xv.z, w2.x, ar.x); ar.y = fmaf(xv.z, w2.y, ar.y);              \
    ar.z = fmaf(xv.z, w2.z, ar.z); ar.w = fmaf(xv.z, w2.w, ar.w);              \
    ar.x = fmaf(xv.w, w3.x, ar.x); ar.y = fmaf(xv.w, w3.y, ar.y);              \
    ar.z = fmaf(xv.w, w3.z, ar.z); ar.w = fmaf(xv.w, w3.w, ar.w);

typedef const __attribute__((address_space(1))) unsigned int* gptr_t;
typedef __attribute__((address_space(3))) unsigned int* lptr_t;

// ================= fused passA (CSR binning) || gemm1 =================
// blocks [0, NBA): passA; blocks [NBA, NBA+NG): 64x64 gemm tile (K=128,
// KT=32, global_load_lds double-buffer). recA = ((colLocal<<17)|row, |ea|)
__global__ __launch_bounds__(256) void buildA_gemm1_k(
        const int* __restrict__ col, const int* __restrict__ row,
        const float* __restrict__ ea, int* __restrict__ gCur,
        uint2* __restrict__ recA, int E, int CAPB, int NB1, int NBA,
        const float* __restrict__ X, const float* __restrict__ W,
        __half* __restrict__ Y, int N) {
    __shared__ __align__(16) float xs[2 * 64 * 32];      // 16KB union (dbuf)
    const int t = threadIdx.x;
    if (blockIdx.x < NBA) {
        // ---------------- passA ----------------
        int* hist = (int*)xs;
        int* base = hist + NB1MAX;
        int* cur  = base + NB1MAX;
        int e0 = blockIdx.x * CHUNK;
        if (t < NB1MAX) { hist[t] = 0; cur[t] = 0; }
        __syncthreads();
        for (int i = t; i < CHUNK; i += 256) {
            int e = e0 + i;
            if (e < E) atomicAdd(&hist[col[e] >> BSH2], 1);
        }
        __syncthreads();
        if (t < NB1) base[t] = atomicAdd(&gCur[t], hist[t]);
        __syncthreads();
        for (int i = t; i < CHUNK; i += 256) {
            int e = e0 + i;
            if (e >= E) continue;
            int c = col[e];
            int b = c >> BSH2;
            int pos = base[b] + atomicAdd(&cur[b], 1);
            if (pos < CAPB)   // statistically impossible overflow; guard anyway
                recA[(size_t)b * CAPB + pos] =
                    make_uint2(((unsigned)(c & (BW2 - 1)) << 17) | (unsigned)row[e],
                               __float_as_uint(fabsf(ea[e])));
        }
    } else {
        // -- gemm1 (K=128, f32 in, KT=32, linear LDS, global_load_lds dbuf) --
        const int K = 128;
        const int row0 = (blockIdx.x - NBA) * 64;
        const int cg = t & 15;
        const int rg = t >> 4;
        const float4* W4 = reinterpret_cast<const float4*>(W);
        // staging: element e in [0,512) float4 units; row=e>>3, k4=e&7.
        // thread t issues e=t and e=t+256; LDS dest linear (base+lane*16).
        const int rrA = t >> 3,          k4A = t & 7;
        const int rrB = (t + 256) >> 3,  k4B = t & 7;   // (t+256)&7 == t&7
        const int grA = min(row0 + rrA, N - 1);
        const int grB = min(row0 + rrB, N - 1);
#define G1_ISSUE(kt, buf)                                                      \
    {                                                                          \
        const float* gA = X + (size_t)grA * K + (kt) + k4A * 4;                \
        const float* gB = X + (size_t)grB * K + (kt) + k4B * 4;                \
        __builtin_amdgcn_global_load_lds((gptr_t)gA,                           \
            (lptr_t)(xs + (buf) * 2048 + t * 4), 16, 0, 0);                    \
        __builtin_amdgcn_global_load_lds((gptr_t)gB,                           \
            (lptr_t)(xs + (buf) * 2048 + (t + 256) * 4), 16, 0, 0);            \
    }
        const float4 z4 = {0.f, 0.f, 0.f, 0.f};
        float4 a0 = z4, a1 = z4, a2 = z4, a3 = z4;
        G1_ISSUE(0, 0)
        __syncthreads();
        for (int kt = 0; kt < 4; ++kt) {
            if (kt < 3) G1_ISSUE((kt + 1) * 32, (kt + 1) & 1)   // prefetch
            const float* xb = xs + (kt & 1) * 2048;
            const float4* xr0 = reinterpret_cast<const float4*>(xb + (rg * 4 + 0) * 32);
            const float4* xr1 = reinterpret_cast<const float4*>(xb + (rg * 4 + 1) * 32);
            const float4* xr2 = reinterpret_cast<const float4*>(xb + (rg * 4 + 2) * 32);
            const float4* xr3 = reinterpret_cast<const float4*>(xb + (rg * 4 + 3) * 32);
#pragma unroll
            for (int k4 = 0; k4 < 8; ++k4) {
                float4 x0 = xr0[k4], x1 = xr1[k4], x2 = xr2[k4], x3 = xr3[k4];
                int kk = kt * 32 + k4 * 4;
                float4 w0 = W4[(kk + 0) * 16 + cg];
                float4 w1 = W4[(kk + 1) * 16 + cg];
                float4 w2 = W4[(kk + 2) * 16 + cg];
                float4 w3 = W4[(kk + 3) * 16 + cg];
                FMA_ROW(a0, x0)
                FMA_ROW(a1, x1)
                FMA_ROW(a2, x2)
                FMA_ROW(a3, x3)
            }
            __syncthreads();   // drains prefetch vmcnt; next buf ready
        }
        int r = row0 + rg * 4;
        __half2* yp0 = reinterpret_cast<__half2*>(Y + (size_t)r * 64 + cg * 4);
        if (r < N) {
            yp0[0] = __float22half2_rn(make_float2(a0.x, a0.y));
            yp0[1] = __float22half2_rn(make_float2(a0.z, a0.w));
        }
        if (r + 1 < N) {
            __half2* yp = yp0 + 32;
            yp[0] = __float22half2_rn(make_float2(a1.x, a1.y));
            yp[1] = __float22half2_rn(make_float2(a1.z, a1.w));
        }
        if (r + 2 < N) {
            __half2* yp = yp0 + 64;
            yp[0] = __float22half2_rn(make_float2(a2.x, a2.y));
            yp[1] = __float22half2_rn(make_float2(a2.z, a2.w));
        }
        if (r + 3 < N) {
            __half2* yp = yp0 + 96;
            yp[0] = __float22half2_rn(make_float2(a3.x, a3.y));
            yp[1] = __float22half2_rn(make_float2(a3.z, a3.w));
        }
#undef G1_ISSUE
    }
}

// ---- pass B: per-bucket binning -> PADDED CSR (row,|ea|) + ptr/cnt + dis ----
__global__ __launch_bounds__(256) void passB_k(const int* __restrict__ gCur,
                                               const uint2* __restrict__ recA,
                                               uint2* __restrict__ rec,
                                               int* __restrict__ ptr,
                                               int* __restrict__ cnt,
                                               float* __restrict__ dis,
                                               int N, int CAPB) {
    __shared__ int hist[BW2], excl[BW2], cur[BW2];
    __shared__ float sumL[BW2];
    __shared__ int part[256];
    int b = blockIdx.x, t = threadIdx.x;
    int nrec = min(gCur[b], CAPB);
    for (int i = t; i < BW2; i += 256) { hist[i] = 0; cur[i] = 0; sumL[i] = 0.f; }
    __syncthreads();
    const uint2* ra = recA + (size_t)b * CAPB;
    for (int i = t; i < nrec; i += 256) {
        uint2 r = ra[i];
        int lc = r.x >> 17;
        atomicAdd(&hist[lc], 1);
        atomicAdd(&sumL[lc], __uint_as_float(r.y));
    }
    __syncthreads();
    // block exclusive scan over 512 PADDED counters (2 per thread)
    int p0 = (hist[t * 2] + PAD - 1) & ~(PAD - 1);
    int p1 = (hist[t * 2 + 1] + PAD - 1) & ~(PAD - 1);
    int s = p0 + p1;
    part[t] = s;
    __syncthreads();
    for (int d = 1; d < 256; d <<= 1) {
        int v = (t >= d) ? part[t - d] : 0;
        __syncthreads();
        part[t] += v;
        __syncthreads();
    }
    int poff = t ? part[t - 1] : 0;
    excl[t * 2] = poff;
    excl[t * 2 + 1] = poff + p0;
    __syncthreads();
    for (int i = t; i < nrec; i += 256) {     // recA bucket is L2-hot (re-read)
        uint2 r = ra[i];
        int lc = r.x >> 17;
        int pos = atomicAdd(&cur[lc], 1);
        rec[(size_t)b * CAPB + excl[lc] + pos] = make_uint2(r.x & 0x1FFFFu, r.y);
    }
    __syncthreads();
    int c0 = b << BSH2;
    for (int i = t; i < BW2; i += 256) {
        int node = c0 + i;
        int hv = hist[i];
        int pc = (hv + PAD - 1) & ~(PAD - 1);
        // fill pad slots with (row=0, w=0): contributes exactly 0, L1-hot row
        for (int j = hv; j < pc; ++j)
            rec[(size_t)b * CAPB + excl[i] + j] = make_uint2(0u, 0u);
        if (node < N) {
            ptr[node] = b * CAPB + excl[i];
            cnt[node] = pc;                        // padded count (mult of 8)
            dis[node] = rsqrtf(sumL[i] + 1.0f);
        }
    }
}

// gemm2: Y[N,64] = X[N,64] @ W[64,64], fp16 in/out, 64x64 tile, LDS stride 68.
__global__ __launch_bounds__(256) void gemm2_k(const __half* __restrict__ X,
                                               const float* __restrict__ W,
                                               __half* __restrict__ Y, int N) {
    const int K = 64, KS = 68;                     // row = 272B = 17x16B
    __shared__ float xs[64 * KS];
    const int tid = threadIdx.x;
    const int row0 = blockIdx.x * 64;
    float4* xs4 = reinterpret_cast<float4*>(xs);
    const __half2* X2 = reinterpret_cast<const __half2*>(X + (size_t)row0 * K);
    for (int idx = tid; idx < 64 * (K / 4); idx += 256) {
        int rl = idx >> 4, k4 = idx & 15;          // K/4 = 16
        int r = row0 + rl;
        if (r < N) {
            float2 fa = __half22float2(X2[2 * idx]);
            float2 fb = __half22float2(X2[2 * idx + 1]);
            xs4[rl * 17 + k4] = float4{fa.x, fa.y, fb.x, fb.y};
        } else xs4[rl * 17 + k4] = float4{0.f, 0.f, 0.f, 0.f};
    }
    __syncthreads();
    const int cg = tid & 15;
    const int rg = tid >> 4;
    const float4* W4 = reinterpret_cast<const float4*>(W);
    const float4* xr0 = reinterpret_cast<const float4*>(xs + (rg * 4 + 0) * KS);
    const float4* xr1 = reinterpret_cast<const float4*>(xs + (rg * 4 + 1) * KS);
    const float4* xr2 = reinterpret_cast<const float4*>(xs + (rg * 4 + 2) * KS);
    const float4* xr3 = reinterpret_cast<const float4*>(xs + (rg * 4 + 3) * KS);
    float4 a0 = {0.f, 0.f, 0.f, 0.f}, a1 = a0, a2 = a0, a3 = a0;
#pragma unroll 2
    for (int k4 = 0; k4 < K / 4; ++k4) {
        float4 x0 = xr0[k4], x1 = xr1[k4], x2 = xr2[k4], x3 = xr3[k4];
        float4 w0 = W4[(k4 * 4 + 0) * 16 + cg];
        float4 w1 = W4[(k4 * 4 + 1) * 16 + cg];
        float4 w2 = W4[(k4 * 4 + 2) * 16 + cg];
        float4 w3 = W4[(k4 * 4 + 3) * 16 + cg];
        FMA_ROW(a0, x0)
        FMA_ROW(a1, x1)
        FMA_ROW(a2, x2)
        FMA_ROW(a3, x3)
    }
    int r = row0 + rg * 4;
    __half2* yp0 = reinterpret_cast<__half2*>(Y + (size_t)r * 64 + cg * 4);
    if (r < N) {
        yp0[0] = __float22half2_rn(make_float2(a0.x, a0.y));
        yp0[1] = __float22half2_rn(make_float2(a0.z, a0.w));
    }
    if (r + 1 < N) {
        __half2* yp = yp0 + 32;
        yp[0] = __float22half2_rn(make_float2(a1.x, a1.y));
        yp[1] = __float22half2_rn(make_float2(a1.z, a1.w));
    }
    if (r + 2 < N) {
        __half2* yp = yp0 + 64;
        yp[0] = __float22half2_rn(make_float2(a2.x, a2.y));
        yp[1] = __float22half2_rn(make_float2(a2.z, a2.w));
    }
    if (r + 3 < N) {
        __half2* yp = yp0 + 96;
        yp[0] = __float22half2_rn(make_float2(a3.x, a3.y));
        yp[1] = __float22half2_rn(make_float2(a3.z, a3.w));
    }
}

// CSR gather aggregation fused with self-loop + bias + ReLU (+ actor logits
// for layer 2). Wave per node; 2 edges per step (half2 lanes); segments
// padded to mult of 8; unroll 2 -> up to 8 gathers in flight per lane.
template <bool WITH_LOGITS>
__global__ __launch_bounds__(256) void agg_fin_k(const int* __restrict__ ptr,
                                                 const int* __restrict__ cnt,
                                                 const uint2* __restrict__ rec,
                                                 const float* __restrict__ dis,
                                                 const __half2* __restrict__ xw2,
                                                 const float* __restrict__ bias,
                                                 __half2* __restrict__ hout,
                                                 const float* __restrict__ aw,
                                                 const float* __restrict__ ab,
                                                 float* __restrict__ logits, int N) {
    int n = blockIdx.x * 4 + (threadIdx.x >> 6);
    if (n >= N) return;
    int lane = threadIdx.x & 63;
    int half_id = lane >> 5;          // 0: even edges, 1: odd edges
    int fl = lane & 31;               // feature pair (2fl, 2fl+1)
    int base = ptr[n], num = cnt[n];  // num % 8 == 0 (padded)
    float ax = 0.f, ay = 0.f;
    for (int k0 = 0; k0 < num; k0 += 64) {
        int rem = min(num - k0, 64);  // multiple of 8
        int r = 0; float w = 0.f;
        if (lane < rem) {
            uint2 rv = rec[(size_t)base + k0 + lane];   // coalesced 512B
            r = (int)rv.x;
            w = __uint_as_float(rv.y) * dis[r];         // 400KB table: L2-hot
        }
#pragma unroll 2
        for (int k = 0; k < rem; k += 8) {
            int i0 = k + half_id;
            int   ra0 = __shfl(r, i0),     ra1 = __shfl(r, i0 + 2);
            int   ra2 = __shfl(r, i0 + 4), ra3 = __shfl(r, i0 + 6);
            float wa0 = __shfl(w, i0),     wa1 = __shfl(w, i0 + 2);
            float wa2 = __shfl(w, i0 + 4), wa3 = __shfl(w, i0 + 6);
            __half2 v0 = xw2[(size_t)ra0 * 32 + fl];
            __half2 v1 = xw2[(size_t)ra1 * 32 + fl];
            __half2 v2 = xw2[(size_t)ra2 * 32 + fl];
            __half2 v3 = xw2[(size_t)ra3 * 32 + fl];
            float2 f;
            f = __half22float2(v0); ax = fmaf(wa0, f.x, ax); ay = fmaf(wa0, f.y, ay);
            f = __half22float2(v1); ax = fmaf(wa1, f.x, ax); ay = fmaf(wa1, f.y, ay);
            f = __half22float2(v2); ax = fmaf(wa2, f.x, ax); ay = fmaf(wa2, f.y, ay);
            f = __half22float2(v3); ax = fmaf(wa3, f.x, ax); ay = fmaf(wa3, f.y, ay);
        }
    }
    // combine even/odd halves (partner lane has same fl)
    ax += __shfl(ax, lane ^ 32);
    ay += __shfl(ay, lane ^ 32);
    if (half_id == 0) {
        float d = dis[n];
        float2 xsv = __half22float2(xw2[(size_t)n * 32 + fl]);
        float2 bb = reinterpret_cast<const float2*>(bias)[fl];
        float2 out;
        out.x = fmaxf(fmaf(d, fmaf(d, xsv.x, ax), bb.x), 0.0f);
        out.y = fmaxf(fmaf(d, fmaf(d, xsv.y, ay), bb.y), 0.0f);
        hout[(size_t)n * 32 + fl] = __float22half2_rn(out);
        if constexpr (WITH_LOGITS) {
            float2 awv = reinterpret_cast<const float2*>(aw)[fl];
            float lg = out.x * awv.x + out.y * awv.y;
            lg += __shfl(lg, lane ^ 1);
            lg += __shfl(lg, lane ^ 2);
            lg += __shfl(lg, lane ^ 4);
            lg += __shfl(lg, lane ^ 8);
            lg += __shfl(lg, lane ^ 16);
            if (lane == 0) logits[n] = lg + ab[0];
        }
    }
}

// Pool-only heads: each 32-lane HALF-WAVE owns a contiguous node chunk
// (batch sorted); fl = lane&31 holds a feature pair; register accumulation,
// one coalesced atomic row per graph transition. Both halves active (R23).
__global__ __launch_bounds__(256) void pool_k(const __half2* __restrict__ h2,
                                              const int* __restrict__ batch,
                                              float* __restrict__ sums,
                                              float* __restrict__ counts,
                                              int N, int C) {
    int grp = blockIdx.x * 8 + (threadIdx.x >> 5);   // 8 half-wave groups/block
    int fl  = threadIdx.x & 31;
    int start = grp * C;
    if (start >= N) return;
    int end = min(start + C, N);
    int cur = batch[start];
    float accx = 0.f, accy = 0.f;
    int cntv = 0;
    for (int i = start; i < end; ++i) {
        float2 v = __half22float2(h2[(size_t)i * 32 + fl]);
        int g = batch[i];                     // group-uniform
        if (g != cur) {
            atomicAdd(&sums[cur * 64 + 2 * fl], accx);
            atomicAdd(&sums[cur * 64 + 2 * fl + 1], accy);
            if (fl == 0) atomicAdd(&counts[cur], (float)cntv);
            accx = 0.f; accy = 0.f; cntv = 0; cur = g;
        }
        accx += v.x; accy += v.y; ++cntv;
    }
    atomicAdd(&sums[cur * 64 + 2 * fl], accx);
    atomicAdd(&sums[cur * 64 + 2 * fl + 1], accy);
    if (fl == 0) atomicAdd(&counts[cur], (float)cntv);
}

__global__ void value_k(const float* __restrict__ sums, const float* __restrict__ counts,
                        const float* __restrict__ cw, const float* __restrict__ cb,
                        float* __restrict__ val) {
    int g = blockIdx.x;
    int lane = threadIdx.x;  // block 64
    float cntv = fmaxf(counts[g], 1.0f);
    float p = (sums[g * 64 + lane] / cntv) * cw[lane];
    for (int off = 32; off; off >>= 1) p += __shfl_down(p, off);
    if (lane == 0) val[g] = p + cb[0];
}

extern "C" void kernel_launch(void* const* d_in, const int* in_sizes, int n_in,
                              void* d_out, int out_size, void* d_ws, size_t ws_size,
                              hipStream_t stream) {
    const float* x     = (const float*)d_in[0];
    const int*   ei    = (const int*)d_in[1];
    const float* ea    = (const float*)d_in[2];
    const int*   batch = (const int*)d_in[3];
    const float* W1    = (const float*)d_in[4];
    const float* b1    = (const float*)d_in[5];
    const float* W2    = (const float*)d_in[6];
    const float* b2    = (const float*)d_in[7];
    const float* aw    = (const float*)d_in[8];
    const float* ab    = (const float*)d_in[9];
    const float* cw    = (const float*)d_in[10];
    const float* cb    = (const float*)d_in[11];

    const int N = in_sizes[3];
    const int E = in_sizes[2];
    const int H = 64, G = 64;
    const int* row = ei;
    const int* col = ei + E;

    const int NB1  = (N + BW2 - 1) >> BSH2;                // coarse buckets (<=256)
    const int CAPB = (((E / NB1) * 3 / 2 + 512) + 1) & ~1; // 1.5x mean (padding slack)
    const int NBA  = (E + CHUNK - 1) / CHUNK;              // passA blocks
    const int NG1  = (N + 63) / 64;                        // gemm1 blocks

    // workspace layout (~60 MB). sums/counts/gCur colocated -> ONE memset.
    float*  sums   = (float*)d_ws;                          // G*H
    float*  counts = sums + G * H;                          // G
    int*    gCur   = (int*)(counts + G);                    // NB1MAX
    float*  dis    = (float*)(gCur + NB1MAX);               // N
    uint2*  recA   = (uint2*)(dis + N);                     // NB1*CAPB (8B rec)
    uint2*  rec    = recA + (size_t)NB1 * CAPB;             // NB1*CAPB
    int*    ptr    = (int*)(rec + (size_t)NB1 * CAPB);      // N
    int*    cnt    = ptr + N;                               // N
    __half* xwh    = (__half*)(cnt + N);                    // N*H fp16
    __half* hbuf   = xwh + (size_t)N * H;                   // N*H fp16

    float* logits = (float*)d_out;              // N
    float* value  = logits + N;                 // G

    // ---- one memset: sums + counts + gCur ----
    hipMemsetAsync(sums, 0, (size_t)(G * H + G + NB1MAX) * 4, stream);

    // ---- fused: CSR passA || gemm1 ----
    buildA_gemm1_k<<<NBA + NG1, 256, 0, stream>>>(col, row, ea, gCur, recA,
                                                  E, CAPB, NB1, NBA,
                                                  x, W1, xwh, N);
    passB_k<<<NB1, 256, 0, stream>>>(gCur, recA, rec, ptr, cnt, dis, N, CAPB);

    // ---- layer 1 aggregation ----
    agg_fin_k<false><<<(N + 3) / 4, 256, 0, stream>>>(ptr, cnt, rec, dis,
        (const __half2*)xwh, b1, (__half2*)hbuf, nullptr, nullptr, nullptr, N);

    // ---- layer 2 (logits fused into epilogue) ----
    gemm2_k<<<(N + 63) / 64, 256, 0, stream>>>(hbuf, W2, xwh, N);
    agg_fin_k<true><<<(N + 3) / 4, 256, 0, stream>>>(ptr, cnt, rec, dis,
        (const __half2*)xwh, b2, (__half2*)hbuf, aw, ab, logits, N);

    // ---- heads: pool (full-wave, 2 chunks/wave) + value ----
    const int GROUPS = 8192;                    // 32-lane chunk processors
    const int C = (N + GROUPS - 1) / GROUPS;    // ~13 nodes per group
    pool_k<<<GROUPS / 8, 256, 0, stream>>>((const __half2*)hbuf, batch, sums, counts, N, C);
    value_k<<<G, 64, 0, stream>>>(sums, counts, cw, cb, value);
}

// Round 26
// 233.610 us; speedup vs baseline: 1.1015x; 1.1015x over previous
//
#include <hip/hip_runtime.h>
#include <hip/hip_fp16.h>

// GNNPolicy forward: 2-layer GCN + actor head + mean-pool critic head.
// N=100K, E=1.6M, H=64, G=64. CSR build: 2-level counting sort; per-node
// segments padded to mult of 8 (uniform 8-edge gather body, unroll 2). xw/h
// fp16 (f32 accum). passA fused with gemm1 (global_load_lds dbuf staging).
// Pool/value separate (R16 lesson). R24: pool_k reverted to R22 form — R23's
// 2x-chunks variant doubled flush atomics/contention (+23us). Long chunks win.

#define TB 256
#define BSH2 9
#define BW2 512          // nodes per coarse bucket
#define CHUNK 4096       // edges per passA block
#define NB1MAX 256       // max coarse buckets (N <= 131072, row fits 17 bits)
#define PAD 8            // per-node segment padding multiple

#define FMA_ROW(ar, xv)                                                        \
    ar.x = fmaf(xv.x, w0.x, ar.x); ar.y = fmaf(xv.x, w0.y, ar.y);              \
    ar.z = fmaf(xv.x, w0.z, ar.z); ar.w = fmaf(xv.x, w0.w, ar.w);              \
    ar.x = fmaf(xv.y, w1.x, ar.x); ar.y = fmaf(xv.y, w1.y, ar.y);              \
    ar.z = fmaf(xv.y, w1.z, ar.z); ar.w = fmaf(xv.y, w1.w, ar.w);              \
    ar.x = fmaf(xv.z, w2.x, ar.x); ar.y = fmaf(xv.z, w2.y, ar.y);              \
    ar.z = fmaf(xv.z, w2.z, ar.z); ar.w = fmaf(xv.z, w2.w, ar.w);              \
    ar.x = fmaf(xv.w, w3.x, ar.x); ar.y = fmaf(xv.w, w3.y, ar.y);              \
    ar.z = fmaf(xv.w, w3.z, ar.z); ar.w = fmaf(xv.w, w3.w, ar.w);

typedef const __attribute__((address_space(1))) unsigned int* gptr_t;
typedef __attribute__((address_space(3))) unsigned int* lptr_t;

// ================= fused passA (CSR binning) || gemm1 =================
// blocks [0, NBA): passA; blocks [NBA, NBA+NG): 64x64 gemm tile (K=128,
// KT=32, global_load_lds double-buffer). recA = ((colLocal<<17)|row, |ea|)
__global__ __launch_bounds__(256) void buildA_gemm1_k(
        const int* __restrict__ col, const int* __restrict__ row,
        const float* __restrict__ ea, int* __restrict__ gCur,
        uint2* __restrict__ recA, int E, int CAPB, int NB1, int NBA,
        const float* __restrict__ X, const float* __restrict__ W,
        __half* __restrict__ Y, int N) {
    __shared__ __align__(16) float xs[2 * 64 * 32];      // 16KB union (dbuf)
    const int t = threadIdx.x;
    if (blockIdx.x < NBA) {
        // ---------------- passA ----------------
        int* hist = (int*)xs;
        int* base = hist + NB1MAX;
        int* cur  = base + NB1MAX;
        int e0 = blockIdx.x * CHUNK;
        if (t < NB1MAX) { hist[t] = 0; cur[t] = 0; }
        __syncthreads();
        for (int i = t; i < CHUNK; i += 256) {
            int e = e0 + i;
            if (e < E) atomicAdd(&hist[col[e] >> BSH2], 1);
        }
        __syncthreads();
        if (t < NB1) base[t] = atomicAdd(&gCur[t], hist[t]);
        __syncthreads();
        for (int i = t; i < CHUNK; i += 256) {
            int e = e0 + i;
            if (e >= E) continue;
            int c = col[e];
            int b = c >> BSH2;
            int pos = base[b] + atomicAdd(&cur[b], 1);
            if (pos < CAPB)   // statistically impossible overflow; guard anyway
                recA[(size_t)b * CAPB + pos] =
                    make_uint2(((unsigned)(c & (BW2 - 1)) << 17) | (unsigned)row[e],
                               __float_as_uint(fabsf(ea[e])));
        }
    } else {
        // -- gemm1 (K=128, f32 in, KT=32, linear LDS, global_load_lds dbuf) --
        const int K = 128;
        const int row0 = (blockIdx.x - NBA) * 64;
        const int cg = t & 15;
        const int rg = t >> 4;
        const float4* W4 = reinterpret_cast<const float4*>(W);
        // staging: element e in [0,512) float4 units; row=e>>3, k4=e&7.
        // thread t issues e=t and e=t+256; LDS dest linear (base+lane*16).
        const int rrA = t >> 3,          k4A = t & 7;
        const int rrB = (t + 256) >> 3,  k4B = t & 7;   // (t+256)&7 == t&7
        const int grA = min(row0 + rrA, N - 1);
        const int grB = min(row0 + rrB, N - 1);
#define G1_ISSUE(kt, buf)                                                      \
    {                                                                          \
        const float* gA = X + (size_t)grA * K + (kt) + k4A * 4;                \
        const float* gB = X + (size_t)grB * K + (kt) + k4B * 4;                \
        __builtin_amdgcn_global_load_lds((gptr_t)gA,                           \
            (lptr_t)(xs + (buf) * 2048 + t * 4), 16, 0, 0);                    \
        __builtin_amdgcn_global_load_lds((gptr_t)gB,                           \
            (lptr_t)(xs + (buf) * 2048 + (t + 256) * 4), 16, 0, 0);            \
    }
        const float4 z4 = {0.f, 0.f, 0.f, 0.f};
        float4 a0 = z4, a1 = z4, a2 = z4, a3 = z4;
        G1_ISSUE(0, 0)
        __syncthreads();
        for (int kt = 0; kt < 4; ++kt) {
            if (kt < 3) G1_ISSUE((kt + 1) * 32, (kt + 1) & 1)   // prefetch
            const float* xb = xs + (kt & 1) * 2048;
            const float4* xr0 = reinterpret_cast<const float4*>(xb + (rg * 4 + 0) * 32);
            const float4* xr1 = reinterpret_cast<const float4*>(xb + (rg * 4 + 1) * 32);
            const float4* xr2 = reinterpret_cast<const float4*>(xb + (rg * 4 + 2) * 32);
            const float4* xr3 = reinterpret_cast<const float4*>(xb + (rg * 4 + 3) * 32);
#pragma unroll
            for (int k4 = 0; k4 < 8; ++k4) {
                float4 x0 = xr0[k4], x1 = xr1[k4], x2 = xr2[k4], x3 = xr3[k4];
                int kk = kt * 32 + k4 * 4;
                float4 w0 = W4[(kk + 0) * 16 + cg];
                float4 w1 = W4[(kk + 1) * 16 + cg];
                float4 w2 = W4[(kk + 2) * 16 + cg];
                float4 w3 = W4[(kk + 3) * 16 + cg];
                FMA_ROW(a0, x0)
                FMA_ROW(a1, x1)
                FMA_ROW(a2, x2)
                FMA_ROW(a3, x3)
            }
            __syncthreads();   // drains prefetch vmcnt; next buf ready
        }
        int r = row0 + rg * 4;
        __half2* yp0 = reinterpret_cast<__half2*>(Y + (size_t)r * 64 + cg * 4);
        if (r < N) {
            yp0[0] = __float22half2_rn(make_float2(a0.x, a0.y));
            yp0[1] = __float22half2_rn(make_float2(a0.z, a0.w));
        }
        if (r + 1 < N) {
            __half2* yp = yp0 + 32;
            yp[0] = __float22half2_rn(make_float2(a1.x, a1.y));
            yp[1] = __float22half2_rn(make_float2(a1.z, a1.w));
        }
        if (r + 2 < N) {
            __half2* yp = yp0 + 64;
            yp[0] = __float22half2_rn(make_float2(a2.x, a2.y));
            yp[1] = __float22half2_rn(make_float2(a2.z, a2.w));
        }
        if (r + 3 < N) {
            __half2* yp = yp0 + 96;
            yp[0] = __float22half2_rn(make_float2(a3.x, a3.y));
            yp[1] = __float22half2_rn(make_float2(a3.z, a3.w));
        }
#undef G1_ISSUE
    }
}

// ---- pass B: per-bucket binning -> PADDED CSR (row,|ea|) + ptr/cnt + dis ----
__global__ __launch_bounds__(256) void passB_k(const int* __restrict__ gCur,
                                               const uint2* __restrict__ recA,
                                               uint2* __restrict__ rec,
                                               int* __restrict__ ptr,
                                               int* __restrict__ cnt,
                                               float* __restrict__ dis,
                                               int N, int CAPB) {
    __shared__ int hist[BW2], excl[BW2], cur[BW2];
    __shared__ float sumL[BW2];
    __shared__ int part[256];
    int b = blockIdx.x, t = threadIdx.x;
    int nrec = min(gCur[b], CAPB);
    for (int i = t; i < BW2; i += 256) { hist[i] = 0; cur[i] = 0; sumL[i] = 0.f; }
    __syncthreads();
    const uint2* ra = recA + (size_t)b * CAPB;
    for (int i = t; i < nrec; i += 256) {
        uint2 r = ra[i];
        int lc = r.x >> 17;
        atomicAdd(&hist[lc], 1);
        atomicAdd(&sumL[lc], __uint_as_float(r.y));
    }
    __syncthreads();
    // block exclusive scan over 512 PADDED counters (2 per thread)
    int p0 = (hist[t * 2] + PAD - 1) & ~(PAD - 1);
    int p1 = (hist[t * 2 + 1] + PAD - 1) & ~(PAD - 1);
    int s = p0 + p1;
    part[t] = s;
    __syncthreads();
    for (int d = 1; d < 256; d <<= 1) {
        int v = (t >= d) ? part[t - d] : 0;
        __syncthreads();
        part[t] += v;
        __syncthreads();
    }
    int poff = t ? part[t - 1] : 0;
    excl[t * 2] = poff;
    excl[t * 2 + 1] = poff + p0;
    __syncthreads();
    for (int i = t; i < nrec; i += 256) {     // recA bucket is L2-hot (re-read)
        uint2 r = ra[i];
        int lc = r.x >> 17;
        int pos = atomicAdd(&cur[lc], 1);
        rec[(size_t)b * CAPB + excl[lc] + pos] = make_uint2(r.x & 0x1FFFFu, r.y);
    }
    __syncthreads();
    int c0 = b << BSH2;
    for (int i = t; i < BW2; i += 256) {
        int node = c0 + i;
        int hv = hist[i];
        int pc = (hv + PAD - 1) & ~(PAD - 1);
        // fill pad slots with (row=0, w=0): contributes exactly 0, L1-hot row
        for (int j = hv; j < pc; ++j)
            rec[(size_t)b * CAPB + excl[i] + j] = make_uint2(0u, 0u);
        if (node < N) {
            ptr[node] = b * CAPB + excl[i];
            cnt[node] = pc;                        // padded count (mult of 8)
            dis[node] = rsqrtf(sumL[i] + 1.0f);
        }
    }
}

// gemm2: Y[N,64] = X[N,64] @ W[64,64], fp16 in/out, 64x64 tile, LDS stride 68.
__global__ __launch_bounds__(256) void gemm2_k(const __half* __restrict__ X,
                                               const float* __restrict__ W,
                                               __half* __restrict__ Y, int N) {
    const int K = 64, KS = 68;                     // row = 272B = 17x16B
    __shared__ float xs[64 * KS];
    const int tid = threadIdx.x;
    const int row0 = blockIdx.x * 64;
    float4* xs4 = reinterpret_cast<float4*>(xs);
    const __half2* X2 = reinterpret_cast<const __half2*>(X + (size_t)row0 * K);
    for (int idx = tid; idx < 64 * (K / 4); idx += 256) {
        int rl = idx >> 4, k4 = idx & 15;          // K/4 = 16
        int r = row0 + rl;
        if (r < N) {
            float2 fa = __half22float2(X2[2 * idx]);
            float2 fb = __half22float2(X2[2 * idx + 1]);
            xs4[rl * 17 + k4] = float4{fa.x, fa.y, fb.x, fb.y};
        } else xs4[rl * 17 + k4] = float4{0.f, 0.f, 0.f, 0.f};
    }
    __syncthreads();
    const int cg = tid & 15;
    const int rg = tid >> 4;
    const float4* W4 = reinterpret_cast<const float4*>(W);
    const float4* xr0 = reinterpret_cast<const float4*>(xs + (rg * 4 + 0) * KS);
    const float4* xr1 = reinterpret_cast<const float4*>(xs + (rg * 4 + 1) * KS);
    const float4* xr2 = reinterpret_cast<const float4*>(xs + (rg * 4 + 2) * KS);
    const float4* xr3 = reinterpret_cast<const float4*>(xs + (rg * 4 + 3) * KS);
    float4 a0 = {0.f, 0.f, 0.f, 0.f}, a1 = a0, a2 = a0, a3 = a0;
#pragma unroll 2
    for (int k4 = 0; k4 < K / 4; ++k4) {
        float4 x0 = xr0[k4], x1 = xr1[k4], x2 = xr2[k4], x3 = xr3[k4];
        float4 w0 = W4[(k4 * 4 + 0) * 16 + cg];
        float4 w1 = W4[(k4 * 4 + 1) * 16 + cg];
        float4 w2 = W4[(k4 * 4 + 2) * 16 + cg];
        float4 w3 = W4[(k4 * 4 + 3) * 16 + cg];
        FMA_ROW(a0, x0)
        FMA_ROW(a1, x1)
        FMA_ROW(a2, x2)
        FMA_ROW(a3, x3)
    }
    int r = row0 + rg * 4;
    __half2* yp0 = reinterpret_cast<__half2*>(Y + (size_t)r * 64 + cg * 4);
    if (r < N) {
        yp0[0] = __float22half2_rn(make_float2(a0.x, a0.y));
        yp0[1] = __float22half2_rn(make_float2(a0.z, a0.w));
    }
    if (r + 1 < N) {
        __half2* yp = yp0 + 32;
        yp[0] = __float22half2_rn(make_float2(a1.x, a1.y));
        yp[1] = __float22half2_rn(make_float2(a1.z, a1.w));
    }
    if (r + 2 < N) {
        __half2* yp = yp0 + 64;
        yp[0] = __float22half2_rn(make_float2(a2.x, a2.y));
        yp[1] = __float22half2_rn(make_float2(a2.z, a2.w));
    }
    if (r + 3 < N) {
        __half2* yp = yp0 + 96;
        yp[0] = __float22half2_rn(make_float2(a3.x, a3.y));
        yp[1] = __float22half2_rn(make_float2(a3.z, a3.w));
    }
}

// CSR gather aggregation fused with self-loop + bias + ReLU (+ actor logits
// for layer 2). Wave per node; 2 edges per step (half2 lanes); segments
// padded to mult of 8; unroll 2 -> up to 8 gathers in flight per lane.
template <bool WITH_LOGITS>
__global__ __launch_bounds__(256) void agg_fin_k(const int* __restrict__ ptr,
                                                 const int* __restrict__ cnt,
                                                 const uint2* __restrict__ rec,
                                                 const float* __restrict__ dis,
                                                 const __half2* __restrict__ xw2,
                                                 const float* __restrict__ bias,
                                                 __half2* __restrict__ hout,
                                                 const float* __restrict__ aw,
                                                 const float* __restrict__ ab,
                                                 float* __restrict__ logits, int N) {
    int n = blockIdx.x * 4 + (threadIdx.x >> 6);
    if (n >= N) return;
    int lane = threadIdx.x & 63;
    int half_id = lane >> 5;          // 0: even edges, 1: odd edges
    int fl = lane & 31;               // feature pair (2fl, 2fl+1)
    int base = ptr[n], num = cnt[n];  // num % 8 == 0 (padded)
    float ax = 0.f, ay = 0.f;
    for (int k0 = 0; k0 < num; k0 += 64) {
        int rem = min(num - k0, 64);  // multiple of 8
        int r = 0; float w = 0.f;
        if (lane < rem) {
            uint2 rv = rec[(size_t)base + k0 + lane];   // coalesced 512B
            r = (int)rv.x;
            w = __uint_as_float(rv.y) * dis[r];         // 400KB table: L2-hot
        }
#pragma unroll 2
        for (int k = 0; k < rem; k += 8) {
            int i0 = k + half_id;
            int   ra0 = __shfl(r, i0),     ra1 = __shfl(r, i0 + 2);
            int   ra2 = __shfl(r, i0 + 4), ra3 = __shfl(r, i0 + 6);
            float wa0 = __shfl(w, i0),     wa1 = __shfl(w, i0 + 2);
            float wa2 = __shfl(w, i0 + 4), wa3 = __shfl(w, i0 + 6);
            __half2 v0 = xw2[(size_t)ra0 * 32 + fl];
            __half2 v1 = xw2[(size_t)ra1 * 32 + fl];
            __half2 v2 = xw2[(size_t)ra2 * 32 + fl];
            __half2 v3 = xw2[(size_t)ra3 * 32 + fl];
            float2 f;
            f = __half22float2(v0); ax = fmaf(wa0, f.x, ax); ay = fmaf(wa0, f.y, ay);
            f = __half22float2(v1); ax = fmaf(wa1, f.x, ax); ay = fmaf(wa1, f.y, ay);
            f = __half22float2(v2); ax = fmaf(wa2, f.x, ax); ay = fmaf(wa2, f.y, ay);
            f = __half22float2(v3); ax = fmaf(wa3, f.x, ax); ay = fmaf(wa3, f.y, ay);
        }
    }
    // combine even/odd halves (partner lane has same fl)
    ax += __shfl(ax, lane ^ 32);
    ay += __shfl(ay, lane ^ 32);
    if (half_id == 0) {
        float d = dis[n];
        float2 xsv = __half22float2(xw2[(size_t)n * 32 + fl]);
        float2 bb = reinterpret_cast<const float2*>(bias)[fl];
        float2 out;
        out.x = fmaxf(fmaf(d, fmaf(d, xsv.x, ax), bb.x), 0.0f);
        out.y = fmaxf(fmaf(d, fmaf(d, xsv.y, ay), bb.y), 0.0f);
        hout[(size_t)n * 32 + fl] = __float22half2_rn(out);
        if constexpr (WITH_LOGITS) {
            float2 awv = reinterpret_cast<const float2*>(aw)[fl];
            float lg = out.x * awv.x + out.y * awv.y;
            lg += __shfl(lg, lane ^ 1);
            lg += __shfl(lg, lane ^ 2);
            lg += __shfl(lg, lane ^ 4);
            lg += __shfl(lg, lane ^ 8);
            lg += __shfl(lg, lane ^ 16);
            if (lane == 0) logits[n] = lg + ab[0];
        }
    }
}

// Pool-only heads: wave per contiguous node chunk (batch sorted); lanes 0-31
// hold feature pairs, register accumulation, flush on graph transition.
// R24: long chunks (4096 waves) minimize flush atomics; R23's 2x-group
// variant doubled them and regressed.
__global__ __launch_bounds__(256) void pool_k(const __half2* __restrict__ h2,
                                              const int* __restrict__ batch,
                                              float* __restrict__ sums,
                                              float* __restrict__ counts,
                                              int N, int C) {
    int wave = blockIdx.x * 4 + (threadIdx.x >> 6);
    int lane = threadIdx.x & 63;
    int start = wave * C;
    if (start >= N) return;
    if (lane >= 32) return;            // half-wave idle (stream is tiny)
    int end = min(start + C, N);
    int fl = lane;
    int cur = batch[start];
    float accx = 0.f, accy = 0.f;
    int cntv = 0;
    for (int i = start; i < end; ++i) {
        float2 v = __half22float2(h2[(size_t)i * 32 + fl]);
        int g = batch[i];                     // wave-uniform
        if (g != cur) {
            atomicAdd(&sums[cur * 64 + 2 * fl], accx);
            atomicAdd(&sums[cur * 64 + 2 * fl + 1], accy);
            if (fl == 0) atomicAdd(&counts[cur], (float)cntv);
            accx = 0.f; accy = 0.f; cntv = 0; cur = g;
        }
        accx += v.x; accy += v.y; ++cntv;
    }
    atomicAdd(&sums[cur * 64 + 2 * fl], accx);
    atomicAdd(&sums[cur * 64 + 2 * fl + 1], accy);
    if (fl == 0) atomicAdd(&counts[cur], (float)cntv);
}

__global__ void value_k(const float* __restrict__ sums, const float* __restrict__ counts,
                        const float* __restrict__ cw, const float* __restrict__ cb,
                        float* __restrict__ val) {
    int g = blockIdx.x;
    int lane = threadIdx.x;  // block 64
    float cntv = fmaxf(counts[g], 1.0f);
    float p = (sums[g * 64 + lane] / cntv) * cw[lane];
    for (int off = 32; off; off >>= 1) p += __shfl_down(p, off);
    if (lane == 0) val[g] = p + cb[0];
}

extern "C" void kernel_launch(void* const* d_in, const int* in_sizes, int n_in,
                              void* d_out, int out_size, void* d_ws, size_t ws_size,
                              hipStream_t stream) {
    const float* x     = (const float*)d_in[0];
    const int*   ei    = (const int*)d_in[1];
    const float* ea    = (const float*)d_in[2];
    const int*   batch = (const int*)d_in[3];
    const float* W1    = (const float*)d_in[4];
    const float* b1    = (const float*)d_in[5];
    const float* W2    = (const float*)d_in[6];
    const float* b2    = (const float*)d_in[7];
    const float* aw    = (const float*)d_in[8];
    const float* ab    = (const float*)d_in[9];
    const float* cw    = (const float*)d_in[10];
    const float* cb    = (const float*)d_in[11];

    const int N = in_sizes[3];
    const int E = in_sizes[2];
    const int H = 64, G = 64;
    const int* row = ei;
    const int* col = ei + E;

    const int NB1  = (N + BW2 - 1) >> BSH2;                // coarse buckets (<=256)
    const int CAPB = (((E / NB1) * 3 / 2 + 512) + 1) & ~1; // 1.5x mean (padding slack)
    const int NBA  = (E + CHUNK - 1) / CHUNK;              // passA blocks
    const int NG1  = (N + 63) / 64;                        // gemm1 blocks

    // workspace layout (~60 MB). sums/counts/gCur colocated -> ONE memset.
    float*  sums   = (float*)d_ws;                          // G*H
    float*  counts = sums + G * H;                          // G
    int*    gCur   = (int*)(counts + G);                    // NB1MAX
    float*  dis    = (float*)(gCur + NB1MAX);               // N
    uint2*  recA   = (uint2*)(dis + N);                     // NB1*CAPB (8B rec)
    uint2*  rec    = recA + (size_t)NB1 * CAPB;             // NB1*CAPB
    int*    ptr    = (int*)(rec + (size_t)NB1 * CAPB);      // N
    int*    cnt    = ptr + N;                               // N
    __half* xwh    = (__half*)(cnt + N);                    // N*H fp16
    __half* hbuf   = xwh + (size_t)N * H;                   // N*H fp16

    float* logits = (float*)d_out;              // N
    float* value  = logits + N;                 // G

    // ---- one memset: sums + counts + gCur ----
    hipMemsetAsync(sums, 0, (size_t)(G * H + G + NB1MAX) * 4, stream);

    // ---- fused: CSR passA || gemm1 ----
    buildA_gemm1_k<<<NBA + NG1, 256, 0, stream>>>(col, row, ea, gCur, recA,
                                                  E, CAPB, NB1, NBA,
                                                  x, W1, xwh, N);
    passB_k<<<NB1, 256, 0, stream>>>(gCur, recA, rec, ptr, cnt, dis, N, CAPB);

    // ---- layer 1 aggregation ----
    agg_fin_k<false><<<(N + 3) / 4, 256, 0, stream>>>(ptr, cnt, rec, dis,
        (const __half2*)xwh, b1, (__half2*)hbuf, nullptr, nullptr, nullptr, N);

    // ---- layer 2 (logits fused into epilogue) ----
    gemm2_k<<<(N + 63) / 64, 256, 0, stream>>>(hbuf, W2, xwh, N);
    agg_fin_k<true><<<(N + 3) / 4, 256, 0, stream>>>(ptr, cnt, rec, dis,
        (const __half2*)xwh, b2, (__half2*)hbuf, aw, ab, logits, N);

    // ---- heads: pool + value (separate kernels; ordering = coherence) ----
    const int WAVES = 4096;
    const int C = (N + WAVES - 1) / WAVES;
    pool_k<<<WAVES / 4, 256, 0, stream>>>((const __half2*)hbuf, batch, sums, counts, N, C);
    value_k<<<G, 64, 0, stream>>>(sums, counts, cw, cb, value);
}